// Round 4
// baseline (155.764 us; speedup 1.0000x reference)
//
#include <hip/hip_runtime.h>
#include <math.h>

#define NF 512
#define NF2 (NF * NF)
#define RPB 4            // FFT rows per block
#define PI_F 3.14159265358979323846f

typedef float2 Row[NF];

// ---------------- radix-2 Stockham FFT-512 over RPB rows in LDS ----------------
// W[k] = (cos(pi k/256), sin(pi k/256)); dsign = -1 forward, +1 inverse.
__device__ inline Row* fft512(Row* SA, Row* SB, const float2* W, int tid, float dsign) {
    int r = tid >> 6, tr = tid & 63;
    Row* S = SA; Row* D = SB;
    int m = 1;
    for (int st = 0; st < 9; ++st) {
        __syncthreads();
#pragma unroll
        for (int q = 0; q < 4; ++q) {
            int b = tr + (q << 6);           // butterfly index 0..255
            int widx = b & ~(m - 1);         // = (b>>st)<<st  -> twiddle idx
            float2 c0 = S[r][b];
            float2 c1 = S[r][b + 256];
            float2 w = W[widx];
            float wre = w.x, wim = dsign * w.y;
            float sx = c0.x + c1.x, sy = c0.y + c1.y;
            float tx = c0.x - c1.x, ty = c0.y - c1.y;
            int o = b + widx;                // = b + j*m
            D[r][o] = make_float2(sx, sy);
            D[r][o + m] = make_float2(tx * wre - ty * wim, tx * wim + ty * wre);
        }
        Row* t = S; S = D; D = t;
        m <<= 1;
    }
    __syncthreads();
    return S;
}

#define FFT_SHARED                                     \
    __shared__ float2 SA[RPB][NF];                     \
    __shared__ float2 SB[RPB][NF];                     \
    __shared__ float2 W[256];                          \
    int tid = threadIdx.x;                             \
    {                                                  \
        float sn, cs;                                  \
        sincosf((PI_F / 256.0f) * (float)tid, &sn, &cs); \
        W[tid] = make_float2(cs, sn);                  \
    }

// Hermitian unpack of one real field from a packed complex spectrum.
// slot 0: field was Re of z;  slot 1: field was Im of z.
__device__ inline float2 unpack_field(const float2* __restrict__ Z, int plane, int slot,
                                      int ky, int kx) {
    const float2* P = Z + (size_t)plane * NF2;
    float2 zr = P[(ky << 9) + kx];
    float2 zm = P[(((NF - ky) & (NF - 1)) << 9) + ((NF - kx) & (NF - 1))];
    if (slot == 0)
        return make_float2(0.5f * (zr.x + zm.x), 0.5f * (zr.y - zm.y));
    else
        return make_float2(0.5f * (zr.y + zm.y), 0.5f * (zm.x - zr.x));
}

// Pass 1 forward, packed: plane p packs two real fields (re + i*im) from A/K.
//  p0=A0+iA1  p1=A2+iK0  p2=K1+iK2  p3=K3+iK4  p4=K5+iK6  p5=K7+iK8  p6=K9
// FFT along y, output transposed: Z[p][ky][x].
__global__ __launch_bounds__(256) void k_fwd_p1(const float* __restrict__ A,
                                                const float* __restrict__ K,
                                                float2* __restrict__ Z) {
    FFT_SHARED
    int p = blockIdx.y;
    const float* bre; int sre, cre;
    const float* bim; int sim, cim;
    switch (p) {
        case 0: bre = A; sre = 3; cre = 0; bim = A; sim = 3; cim = 1; break;
        case 1: bre = A; sre = 3; cre = 2; bim = K; sim = 10; cim = 0; break;
        case 2: bre = K; sre = 10; cre = 1; bim = K; sim = 10; cim = 2; break;
        case 3: bre = K; sre = 10; cre = 3; bim = K; sim = 10; cim = 4; break;
        case 4: bre = K; sre = 10; cre = 5; bim = K; sim = 10; cim = 6; break;
        case 5: bre = K; sre = 10; cre = 7; bim = K; sim = 10; cim = 8; break;
        default: bre = K; sre = 10; cre = 9; bim = nullptr; sim = 0; cim = 0; break;
    }
    int x0 = blockIdx.x * RPB;
    for (int i = tid; i < RPB * NF; i += 256) {
        int r = i >> 9, y = i & (NF - 1);
        int idx = ((x0 + r) << 9) + y;
        float vr = bre[idx * sre + cre];
        float vi = bim ? bim[idx * sim + cim] : 0.0f;
        SA[r][y] = make_float2(vr, vi);
    }
    Row* R = fft512(SA, SB, W, tid, -1.0f);
    for (int i = tid; i < RPB * NF; i += 256) {
        int r = i & (RPB - 1), ky = i >> 2;
        Z[(size_t)((p << 9) + ky) * NF + x0 + r] = R[r][ky];
    }
}

// Pass 2: in-place FFT of contiguous rows (all 7 packed planes in one launch).
__global__ __launch_bounds__(256) void k_fft_rows(float2* __restrict__ data, float dsign) {
    FFT_SHARED
    int R0 = blockIdx.x * RPB;
    for (int i = tid; i < RPB * NF; i += 256) {
        int r = i >> 9, x = i & (NF - 1);
        SA[r][x] = data[(size_t)(R0 + r) * NF + x];
    }
    Row* R = fft512(SA, SB, W, tid, dsign);
    for (int i = tid; i < RPB * NF; i += 256) {
        int r = i >> 9, x = i & (NF - 1);
        data[(size_t)(R0 + r) * NF + x] = R[r][x];
    }
}

// Paired spectral multiply + inverse FFT along kx.
// Plane j handles kernels k1=2j, k2=2j+1:  S = (fK1*fA_{c0[k1]} + i*fK2*fA_{c0[k2]})*sgn
// ifft2(S) later yields U_{k1} = Re, U_{k2} = Im.  Writes tmp[j][x][ky].
__global__ __launch_bounds__(256) void k_mulinv_p1(const float2* __restrict__ Z,
                                                   const int* __restrict__ c0,
                                                   float2* __restrict__ tmp) {
    FFT_SHARED
    int j = blockIdx.y;
    int k1 = 2 * j, k2 = 2 * j + 1;
    // K_k -> (plane, slot):  k==0 -> (1, Im);  k>=1 -> (2 + (k-1)/2, (k-1)&1)
    int pK1 = (k1 == 0) ? 1 : 2 + ((k1 - 1) >> 1);
    int sK1 = (k1 == 0) ? 1 : ((k1 - 1) & 1);
    int pK2 = 2 + ((k2 - 1) >> 1);          // k2 >= 1 always
    int sK2 = (k2 - 1) & 1;
    // A_c -> (plane, slot): c>>1, c&1   (A0->p0.Re, A1->p0.Im, A2->p1.Re)
    int cA1 = c0[k1], cA2 = c0[k2];
    int pA1 = cA1 >> 1, sA1 = cA1 & 1;
    int pA2 = cA2 >> 1, sA2 = cA2 & 1;
    bool sameA = (cA1 == cA2);

    int ky0 = blockIdx.x * RPB;
    for (int i = tid; i < RPB * NF; i += 256) {
        int r = i >> 9, kx = i & (NF - 1);
        int ky = ky0 + r;
        float2 fk1 = unpack_field(Z, pK1, sK1, ky, kx);
        float2 fk2 = unpack_field(Z, pK2, sK2, ky, kx);
        float2 fa1 = unpack_field(Z, pA1, sA1, ky, kx);
        float2 fa2 = sameA ? fa1 : unpack_field(Z, pA2, sA2, ky, kx);
        float t1x = fk1.x * fa1.x - fk1.y * fa1.y;
        float t1y = fk1.x * fa1.y + fk1.y * fa1.x;
        float t2x = fk2.x * fa2.x - fk2.y * fa2.y;
        float t2y = fk2.x * fa2.y + fk2.y * fa2.x;
        float sgn = ((kx + ky) & 1) ? -1.0f : 1.0f;
        SA[r][kx] = make_float2((t1x - t2y) * sgn, (t1y + t2x) * sgn);
    }
    Row* R = fft512(SA, SB, W, tid, +1.0f);
    for (int i = tid; i < RPB * NF; i += 256) {
        int r = i & (RPB - 1), x = i >> 2;
        tmp[(size_t)(j * NF + x) * NF + ky0 + r] = R[r][x];
    }
}

// Inverse FFT along ky + dual growth epilogue.
// tmp[j][x][ky] -> G[2j][x][y] (from Re), G[2j+1][x][y] (from Im).
__global__ __launch_bounds__(256) void k_inv_p2g(const float2* __restrict__ tmp,
                                                 const float* __restrict__ mm,
                                                 const float* __restrict__ ss,
                                                 const float* __restrict__ hh,
                                                 float* __restrict__ G) {
    FFT_SHARED
    int j = blockIdx.y;
    int k1 = 2 * j, k2 = 2 * j + 1;
    int x0 = blockIdx.x * RPB;
    for (int i = tid; i < RPB * NF; i += 256) {
        int r = i >> 9, ky = i & (NF - 1);
        SA[r][ky] = tmp[(size_t)(j * NF + x0 + r) * NF + ky];
    }
    Row* R = fft512(SA, SB, W, tid, +1.0f);
    float m1 = mm[k1], s1 = ss[k1], h1 = hh[k1];
    float m2 = mm[k2], s2 = ss[k2], h2 = hh[k2];
    float i2s1 = 1.0f / (2.0f * s1 * s1);
    float i2s2 = 1.0f / (2.0f * s2 * s2);
    const float scale = 1.0f / ((float)NF * (float)NF);
    for (int i = tid; i < RPB * NF; i += 256) {
        int r = i >> 9, y = i & (NF - 1);
        float2 v = R[r][y];
        float u1 = v.x * scale, u2 = v.y * scale;
        float d1 = u1 - m1, d2 = u2 - m2;
        size_t base = (size_t)(x0 + r) * NF + y;
        G[(size_t)k1 * NF2 + base] = (2.0f * expf(-d1 * d1 * i2s1) - 1.0f) * h1;
        G[(size_t)k2 * NF2 + base] = (2.0f * expf(-d2 * d2 * i2s2) - 1.0f) * h2;
    }
}

// U'[c] = sum_k G[k] * c1_mat[k][c];  As = sum_c A[..c]
__global__ __launch_bounds__(256) void k_combine(const float* __restrict__ G,
                                                 const int* __restrict__ c1,
                                                 const float* __restrict__ A,
                                                 float* __restrict__ Up,
                                                 float* __restrict__ As) {
    int id = blockIdx.x * 256 + threadIdx.x;
    float a0 = 0.f, a1 = 0.f, a2 = 0.f;
#pragma unroll
    for (int k = 0; k < 10; ++k) {
        float g = G[k * NF2 + id];
        a0 += g * (float)c1[k * 3 + 0];
        a1 += g * (float)c1[k * 3 + 1];
        a2 += g * (float)c1[k * 3 + 2];
    }
    Up[id] = a0;
    Up[NF2 + id] = a1;
    Up[2 * NF2 + id] = a2;
    As[id] = A[id * 3 + 0] + A[id * 3 + 1] + A[id * 3 + 2];
}

// Sobel flow field -> mu (planar: [d*3+c][x][y])
__global__ __launch_bounds__(256) void k_flow(const float* __restrict__ Up,
                                              const float* __restrict__ As,
                                              const float* __restrict__ A,
                                              float* __restrict__ mu) {
    int id = blockIdx.x * 256 + threadIdx.x;
    int x = id >> 9, y = id & (NF - 1);
    int xm = (x - 1) & (NF - 1), xp = (x + 1) & (NF - 1);
    int ym = (y - 1) & (NF - 1), yp = (y + 1) & (NF - 1);

    auto grad = [&](const float* f, float& gx, float& gy) {
        float fmm = f[xm * NF + ym], fm0 = f[xm * NF + y], fmp = f[xm * NF + yp];
        float f0m = f[x * NF + ym], f0p = f[x * NF + yp];
        float fpm = f[xp * NF + ym], fp0 = f[xp * NF + y], fpp = f[xp * NF + yp];
        gx = (fpm + 2.0f * fp0 + fpp - fmm - 2.0f * fm0 - fmp) * 0.125f;
        gy = (fmp + 2.0f * f0p + fpp - fmm - 2.0f * f0m - fpm) * 0.125f;
    };

    float gax, gay;
    grad(As, gax, gay);
    float px = (float)x + 0.5f, py = (float)y + 0.5f;
#pragma unroll
    for (int c = 0; c < 3; ++c) {
        float gux, guy;
        grad(Up + c * NF2, gux, guy);
        float a = A[id * 3 + c];
        float al = fminf(a * a, 1.0f);   // clip((A/1)^2, 0, 1); a^2 >= 0
        float Fx = gux * (1.0f - al) - gax * al;
        float Fy = guy * (1.0f - al) - gay * al;
        Fx = fminf(fmaxf(Fx, -4.35f), 4.35f);   // ma = DD - SIGMA
        Fy = fminf(fmaxf(Fy, -4.35f), 4.35f);
        mu[c * NF2 + id] = px + 0.2f * Fx;       // DT = 0.2
        mu[(3 + c) * NF2 + id] = py + 0.2f * Fy;
    }
}

// Reintegration: gather over exact 5x5 support (shifts beyond +-2 have area == 0).
__global__ __launch_bounds__(256) void k_reint(const float* __restrict__ A,
                                               const float* __restrict__ mu,
                                               float* __restrict__ out) {
    __shared__ float sA[3][36 * 36];
    __shared__ float sM[6][36 * 36];
    int tid = threadIdx.x;
    int x0 = blockIdx.x * 32, y0 = blockIdx.y * 32;
    for (int i = tid; i < 36 * 36; i += 256) {
        int lx = i / 36, ly = i - lx * 36;
        int xg = (x0 - 2 + lx) & (NF - 1);
        int yg = (y0 - 2 + ly) & (NF - 1);
        int gid = xg * NF + yg;
        sA[0][i] = A[gid * 3 + 0];
        sA[1][i] = A[gid * 3 + 1];
        sA[2][i] = A[gid * 3 + 2];
#pragma unroll
        for (int p = 0; p < 6; ++p) sM[p][i] = mu[p * NF2 + gid];
    }
    __syncthreads();

    const float INV_NORM = (float)(1.0 / (4.0 * 0.65 * 0.65));
    int cy = tid & 31, cx0 = tid >> 5;
    for (int sidx = 0; sidx < 4; ++sidx) {
        int cx = cx0 + 8 * sidx;
        int x = x0 + cx, y = y0 + cy;
        float px = (float)x + 0.5f, py = (float)y + 0.5f;
        float acc0 = 0.f, acc1 = 0.f, acc2 = 0.f;
#pragma unroll
        for (int dx = 0; dx < 5; ++dx)
#pragma unroll
            for (int dy = 0; dy < 5; ++dy) {
                int li = (cx + dx) * 36 + (cy + dy);
#pragma unroll
                for (int c = 0; c < 3; ++c) {
                    float mux = sM[c][li], muy = sM[3 + c][li];
                    float szx = 0.5f - fabsf(px - mux) + 0.65f;
                    float szy = 0.5f - fabsf(py - muy) + 0.65f;
                    szx = fminf(fmaxf(szx, 0.0f), 1.0f);   // clip_hi = min(1, 2*sigma) = 1
                    szy = fminf(fmaxf(szy, 0.0f), 1.0f);
                    float area = szx * szy * INV_NORM;
                    float v = sA[c][li] * area;
                    if (c == 0) acc0 += v;
                    else if (c == 1) acc1 += v;
                    else acc2 += v;
                }
            }
        int gid = x * NF + y;
        out[gid * 3 + 0] = acc0;
        out[gid * 3 + 1] = acc1;
        out[gid * 3 + 2] = acc2;
    }
}

extern "C" void kernel_launch(void* const* d_in, const int* in_sizes, int n_in,
                              void* d_out, int out_size, void* d_ws, size_t ws_size,
                              hipStream_t stream) {
    (void)in_sizes; (void)n_in; (void)out_size; (void)ws_size;
    const float* A  = (const float*)d_in[0];
    const float* nK = (const float*)d_in[1];
    const float* m  = (const float*)d_in[2];
    const float* s  = (const float*)d_in[3];
    const float* h  = (const float*)d_in[4];
    const int*   c0 = (const int*)d_in[5];
    const int*   c1 = (const int*)d_in[6];
    float* out = (float*)d_out;

    char* ws = (char*)d_ws;
    // Z:   7 packed complex planes  = 14,680,064 B  @ 0
    // tmp: 5 complex planes         = 10,485,760 B  @ 14,680,064
    // Aliases into dead regions:
    //   G  (10 real planes, 10,485,760 B) @ 0           (Z dead after mulinv)
    //   Up (3 real planes,   3,145,728 B) @ 10,485,760  (after G, inside Z region)
    //   As (1 real plane,    1,048,576 B) @ 13,631,488  (fills Z region exactly)
    //   mu (6 real planes,   6,291,456 B) @ 14,680,064  (tmp dead after inv_p2g)
    // Total ws usage: 25,165,824 B.
    float2* Z   = (float2*)ws;
    float2* tmp = (float2*)(ws + 14680064);
    float*  G   = (float*)ws;
    float*  Up  = (float*)(ws + 10485760);
    float*  As  = (float*)(ws + 13631488);
    float*  mu  = (float*)(ws + 14680064);

    dim3 blk(256);
    k_fwd_p1<<<dim3(NF / RPB, 7), blk, 0, stream>>>(A, nK, Z);
    k_fft_rows<<<dim3(7 * NF / RPB), blk, 0, stream>>>(Z, -1.0f);
    k_mulinv_p1<<<dim3(NF / RPB, 5), blk, 0, stream>>>(Z, c0, tmp);
    k_inv_p2g<<<dim3(NF / RPB, 5),   blk, 0, stream>>>(tmp, m, s, h, G);
    k_combine<<<dim3(NF2 / 256), blk, 0, stream>>>(G, c1, A, Up, As);
    k_flow<<<dim3(NF2 / 256),    blk, 0, stream>>>(Up, As, A, mu);
    k_reint<<<dim3(16, 16),      blk, 0, stream>>>(A, mu, out);
}

// Round 6
// 142.543 us; speedup vs baseline: 1.0927x; 1.0927x over previous
//
#include <hip/hip_runtime.h>
#include <math.h>

#define NF 512
#define NF2 (NF * NF)
#define RPB 4                 // FFT rows per block (4 rows x 64 threads)
#define ROWLEN 580            // LPAD(511)=574 max; 580 -> row stride % 32 words == 8 (bank stagger)
#define PI_F 3.14159265358979323846f

#define LPAD(q) ((q) + ((q) >> 3))   // LDS pad: 4 words/bank (= wave64 minimum) on butterfly writes

__device__ inline float2 cadd(float2 a, float2 b) { return make_float2(a.x + b.x, a.y + b.y); }
__device__ inline float2 csub(float2 a, float2 b) { return make_float2(a.x - b.x, a.y - b.y); }
__device__ inline float2 cmul(float2 a, float2 b) {
    return make_float2(a.x * b.x - a.y * b.y, a.x * b.y + a.y * b.x);
}

// 8-point DFT in registers, natural order in/out. dsign=-1 fwd, +1 inv.
__device__ inline void fft8(float2 x[8], float dsign) {
    const float s = 0.70710678118654752440f;
    float2 a0 = cadd(x[0], x[4]), a1 = cadd(x[1], x[5]);
    float2 a2 = cadd(x[2], x[6]), a3 = cadd(x[3], x[7]);
    float2 b0 = csub(x[0], x[4]), b1 = csub(x[1], x[5]);
    float2 b2 = csub(x[2], x[6]), b3 = csub(x[3], x[7]);
    b1 = cmul(b1, make_float2(s, dsign * s));                 // w8^1
    b2 = make_float2(-dsign * b2.y, dsign * b2.x);            // * (0, dsign) = w8^2
    b3 = cmul(b3, make_float2(-s, dsign * s));                // w8^3
    float2 c0 = cadd(a0, a2), c1 = cadd(a1, a3);
    float2 c2 = csub(a0, a2), c3 = csub(a1, a3);
    c3 = make_float2(-dsign * c3.y, dsign * c3.x);
    float2 d0 = cadd(b0, b2), d1 = cadd(b1, b3);
    float2 d2 = csub(b0, b2), d3 = csub(b1, b3);
    d3 = make_float2(-dsign * d3.y, dsign * d3.x);
    x[0] = cadd(c0, c1); x[4] = csub(c0, c1);
    x[2] = cadd(c2, c3); x[6] = csub(c2, c3);
    x[1] = cadd(d0, d1); x[5] = csub(d0, d1);
    x[3] = cadd(d2, d3); x[7] = csub(d2, d3);
}

// x[p] *= wb^p, p=1..7 (wb already carries dsign)
__device__ inline void twiddle8(float2 x[8], float2 wb) {
    float2 tw = wb;
    x[1] = cmul(x[1], tw); tw = cmul(tw, wb);
    x[2] = cmul(x[2], tw); tw = cmul(tw, wb);
    x[3] = cmul(x[3], tw); tw = cmul(tw, wb);
    x[4] = cmul(x[4], tw); tw = cmul(tw, wb);
    x[5] = cmul(x[5], tw); tw = cmul(tw, wb);
    x[6] = cmul(x[6], tw); tw = cmul(tw, wb);
    x[7] = cmul(x[7], tw);
}

// Radix-8 Stockham FFT-512. In: x[j] = data[b + 64j]. Out: x[p] = Y[64p + b].
// Delta-function proof (r5): Y[64r+8q+p] = w512^{n*p} w8^{u*q} w64^{v*q} w8^{v*r} = X[k]. 
// Contains 2 internal barriers; after return bufA is reusable, bufB is NOT.
__device__ inline void fft512_regs(float2 x[8], int b, float2* bufA, float2* bufB,
                                   const float2* Wt, float dsign) {
    // stage 0: m=1, u=b, v=0
    fft8(x, dsign);
    float2 wb0 = make_float2(Wt[b].x, dsign * Wt[b].y);
    twiddle8(x, wb0);
#pragma unroll
    for (int p = 0; p < 8; ++p) bufA[9 * b + p] = x[p];   // LPAD(8b+p) = 9b+p
    __syncthreads();
    // stage 1: m=8, u=b>>3, v=b&7
#pragma unroll
    for (int j = 0; j < 8; ++j) x[j] = bufA[LPAD(b + 64 * j)];
    fft8(x, dsign);
    int u = b >> 3, v = b & 7;
    float2 wb1 = make_float2(Wt[b & ~7].x, dsign * Wt[b & ~7].y);   // W512[8u]
    twiddle8(x, wb1);
    int base = u * 64 + v;
#pragma unroll
    for (int p = 0; p < 8; ++p) bufB[LPAD(base + 8 * p)] = x[p];
    __syncthreads();
    // stage 2: m=64, u=0 -> no twiddles
#pragma unroll
    for (int j = 0; j < 8; ++j) x[j] = bufB[LPAD(b + 64 * j)];
    fft8(x, dsign);
}

#define FFT_PRE                                                    \
    __shared__ float2 SHA[RPB][ROWLEN];                            \
    __shared__ float2 SHB[RPB][ROWLEN];                            \
    __shared__ float2 Wt[512];                                     \
    int tid = threadIdx.x;                                         \
    int rr_ = tid >> 6, bb_ = tid & 63;                            \
    {                                                              \
        float sn, cs;                                              \
        sincosf((PI_F / 256.0f) * (float)tid, &sn, &cs);           \
        Wt[tid] = make_float2(cs, sn);                             \
        sincosf((PI_F / 256.0f) * (float)(tid + 256), &sn, &cs);   \
        Wt[tid + 256] = make_float2(cs, sn);                       \
    }

// Hermitian unpack of one real field from a packed complex spectrum.
__device__ inline float2 unpack_field(const float2* __restrict__ Z, int plane, int slot,
                                      int ky, int kx) {
    const float2* P = Z + (size_t)plane * NF2;
    float2 zr = P[(ky << 9) + kx];
    float2 zm = P[(((NF - ky) & (NF - 1)) << 9) + ((NF - kx) & (NF - 1))];
    if (slot == 0)
        return make_float2(0.5f * (zr.x + zm.x), 0.5f * (zr.y - zm.y));
    else
        return make_float2(0.5f * (zr.y + zm.y), 0.5f * (zm.x - zr.x));
}

// Pass 1 forward, packed pairs of real planes:
//  p0=A0+iA1  p1=A2+iK0  p2=K1+iK2  p3=K3+iK4  p4=K5+iK6  p5=K7+iK8  p6=K9
// FFT along y, transposed store: Z[p][ky][x].
__global__ __launch_bounds__(256) void k_fwd_p1(const float* __restrict__ A,
                                                const float* __restrict__ K,
                                                float2* __restrict__ Z) {
    FFT_PRE
    int pl = blockIdx.y;
    const float* bre; int sre, cre;
    const float* bim; int sim, cim;
    switch (pl) {
        case 0: bre = A; sre = 3; cre = 0; bim = A; sim = 3; cim = 1; break;
        case 1: bre = A; sre = 3; cre = 2; bim = K; sim = 10; cim = 0; break;
        case 2: bre = K; sre = 10; cre = 1; bim = K; sim = 10; cim = 2; break;
        case 3: bre = K; sre = 10; cre = 3; bim = K; sim = 10; cim = 4; break;
        case 4: bre = K; sre = 10; cre = 5; bim = K; sim = 10; cim = 6; break;
        case 5: bre = K; sre = 10; cre = 7; bim = K; sim = 10; cim = 8; break;
        default: bre = K; sre = 10; cre = 9; bim = nullptr; sim = 0; cim = 0; break;
    }
    int x0 = blockIdx.x * RPB;
    int row = x0 + rr_;
    float2 x[8];
#pragma unroll
    for (int j = 0; j < 8; ++j) {
        int idx = (row << 9) + bb_ + 64 * j;
        float vr = bre[idx * sre + cre];
        float vi = bim ? bim[idx * sim + cim] : 0.0f;
        x[j] = make_float2(vr, vi);
    }
    __syncthreads();                       // Wt table ready
    fft512_regs(x, bb_, &SHA[rr_][0], &SHB[rr_][0], Wt, -1.0f);
    // transpose via SHA (safe: all stage-1 SHA reads completed before internal barrier 2)
#pragma unroll
    for (int p2 = 0; p2 < 8; ++p2) SHA[rr_][LPAD(64 * p2 + bb_)] = x[p2];
    __syncthreads();
    for (int i = tid; i < RPB * NF; i += 256) {
        int r2 = i & (RPB - 1), ky = i >> 2;
        Z[(size_t)((pl << 9) + ky) * NF + x0 + r2] = SHA[r2][LPAD(ky)];
    }
}

// Pass 2: in-place FFT of contiguous rows (all 7 packed planes, one launch).
__global__ __launch_bounds__(256) void k_fft_rows(float2* __restrict__ data, float dsign) {
    FFT_PRE
    int R0 = blockIdx.x * RPB;
    size_t rowbase = (size_t)(R0 + rr_) * NF;
    float2 x[8];
#pragma unroll
    for (int j = 0; j < 8; ++j) x[j] = data[rowbase + bb_ + 64 * j];
    __syncthreads();
    fft512_regs(x, bb_, &SHA[rr_][0], &SHB[rr_][0], Wt, dsign);
#pragma unroll
    for (int p2 = 0; p2 < 8; ++p2) SHA[rr_][LPAD(64 * p2 + bb_)] = x[p2];
    __syncthreads();
    for (int i = tid; i < RPB * NF; i += 256) {
        int r2 = i >> 9, xx = i & (NF - 1);
        data[(size_t)(R0 + r2) * NF + xx] = SHA[r2][LPAD(xx)];
    }
}

// Paired spectral multiply + inverse FFT along kx, transposed store tmp[j][x][ky].
__global__ __launch_bounds__(256) void k_mulinv_p1(const float2* __restrict__ Z,
                                                   const int* __restrict__ c0,
                                                   float2* __restrict__ tmp) {
    FFT_PRE
    int jp = blockIdx.y;
    int k1 = 2 * jp, k2 = 2 * jp + 1;
    int pK1 = (k1 == 0) ? 1 : 2 + ((k1 - 1) >> 1);
    int sK1 = (k1 == 0) ? 1 : ((k1 - 1) & 1);
    int pK2 = 2 + ((k2 - 1) >> 1);
    int sK2 = (k2 - 1) & 1;
    int cA1 = c0[k1], cA2 = c0[k2];
    int pA1 = cA1 >> 1, sA1 = cA1 & 1;
    int pA2 = cA2 >> 1, sA2 = cA2 & 1;
    bool sameA = (cA1 == cA2);

    int ky0 = blockIdx.x * RPB;
    int ky = ky0 + rr_;
    float2 x[8];
#pragma unroll
    for (int jj = 0; jj < 8; ++jj) {
        int kx = bb_ + 64 * jj;
        float2 fk1 = unpack_field(Z, pK1, sK1, ky, kx);
        float2 fk2 = unpack_field(Z, pK2, sK2, ky, kx);
        float2 fa1 = unpack_field(Z, pA1, sA1, ky, kx);
        float2 fa2 = sameA ? fa1 : unpack_field(Z, pA2, sA2, ky, kx);
        float t1x = fk1.x * fa1.x - fk1.y * fa1.y;
        float t1y = fk1.x * fa1.y + fk1.y * fa1.x;
        float t2x = fk2.x * fa2.x - fk2.y * fa2.y;
        float t2y = fk2.x * fa2.y + fk2.y * fa2.x;
        float sgn = ((kx + ky) & 1) ? -1.0f : 1.0f;
        x[jj] = make_float2((t1x - t2y) * sgn, (t1y + t2x) * sgn);
    }
    __syncthreads();
    fft512_regs(x, bb_, &SHA[rr_][0], &SHB[rr_][0], Wt, +1.0f);
#pragma unroll
    for (int p2 = 0; p2 < 8; ++p2) SHA[rr_][LPAD(64 * p2 + bb_)] = x[p2];
    __syncthreads();
    for (int i = tid; i < RPB * NF; i += 256) {
        int r2 = i & (RPB - 1), xx = i >> 2;
        tmp[(size_t)(jp * NF + xx) * NF + ky0 + r2] = SHA[r2][LPAD(xx)];
    }
}

// Inverse FFT along ky + dual growth epilogue, coalesced store straight from regs.
__global__ __launch_bounds__(256) void k_inv_p2g(const float2* __restrict__ tmp,
                                                 const float* __restrict__ mm,
                                                 const float* __restrict__ ss,
                                                 const float* __restrict__ hh,
                                                 float* __restrict__ G) {
    FFT_PRE
    int jp = blockIdx.y;
    int k1 = 2 * jp, k2 = 2 * jp + 1;
    int x0 = blockIdx.x * RPB;
    int row = x0 + rr_;
    size_t base = (size_t)(jp * NF + row) * NF;
    float2 x[8];
#pragma unroll
    for (int j2 = 0; j2 < 8; ++j2) x[j2] = tmp[base + bb_ + 64 * j2];
    __syncthreads();
    fft512_regs(x, bb_, &SHA[rr_][0], &SHB[rr_][0], Wt, +1.0f);
    float m1 = mm[k1], s1 = ss[k1], h1 = hh[k1];
    float m2 = mm[k2], s2 = ss[k2], h2 = hh[k2];
    float i2s1 = 1.0f / (2.0f * s1 * s1);
    float i2s2 = 1.0f / (2.0f * s2 * s2);
    const float scale = 1.0f / ((float)NF * (float)NF);
#pragma unroll
    for (int p2 = 0; p2 < 8; ++p2) {
        int y = 64 * p2 + bb_;
        float u1 = x[p2].x * scale, u2 = x[p2].y * scale;
        float d1 = u1 - m1, d2 = u2 - m2;
        size_t o = (size_t)row * NF + y;
        G[(size_t)k1 * NF2 + o] = (2.0f * expf(-d1 * d1 * i2s1) - 1.0f) * h1;
        G[(size_t)k2 * NF2 + o] = (2.0f * expf(-d2 * d2 * i2s2) - 1.0f) * h2;
    }
}

// U'[c] = sum_k G[k] * c1_mat[k][c];  As = sum_c A[..c]
__global__ __launch_bounds__(256) void k_combine(const float* __restrict__ G,
                                                 const int* __restrict__ c1,
                                                 const float* __restrict__ A,
                                                 float* __restrict__ Up,
                                                 float* __restrict__ As) {
    int id = blockIdx.x * 256 + threadIdx.x;
    float a0 = 0.f, a1 = 0.f, a2 = 0.f;
#pragma unroll
    for (int k = 0; k < 10; ++k) {
        float g = G[k * NF2 + id];
        a0 += g * (float)c1[k * 3 + 0];
        a1 += g * (float)c1[k * 3 + 1];
        a2 += g * (float)c1[k * 3 + 2];
    }
    Up[id] = a0;
    Up[NF2 + id] = a1;
    Up[2 * NF2 + id] = a2;
    As[id] = A[id * 3 + 0] + A[id * 3 + 1] + A[id * 3 + 2];
}

// Sobel flow field -> mu (planar: [d*3+c][x][y])
__global__ __launch_bounds__(256) void k_flow(const float* __restrict__ Up,
                                              const float* __restrict__ As,
                                              const float* __restrict__ A,
                                              float* __restrict__ mu) {
    int id = blockIdx.x * 256 + threadIdx.x;
    int x = id >> 9, y = id & (NF - 1);
    int xm = (x - 1) & (NF - 1), xp = (x + 1) & (NF - 1);
    int ym = (y - 1) & (NF - 1), yp = (y + 1) & (NF - 1);

    auto grad = [&](const float* f, float& gx, float& gy) {
        float fmm = f[xm * NF + ym], fm0 = f[xm * NF + y], fmp = f[xm * NF + yp];
        float f0m = f[x * NF + ym], f0p = f[x * NF + yp];
        float fpm = f[xp * NF + ym], fp0 = f[xp * NF + y], fpp = f[xp * NF + yp];
        gx = (fpm + 2.0f * fp0 + fpp - fmm - 2.0f * fm0 - fmp) * 0.125f;
        gy = (fmp + 2.0f * f0p + fpp - fmm - 2.0f * f0m - fpm) * 0.125f;
    };

    float gax, gay;
    grad(As, gax, gay);
    float px = (float)x + 0.5f, py = (float)y + 0.5f;
#pragma unroll
    for (int c = 0; c < 3; ++c) {
        float gux, guy;
        grad(Up + c * NF2, gux, guy);
        float a = A[id * 3 + c];
        float al = fminf(a * a, 1.0f);
        float Fx = gux * (1.0f - al) - gax * al;
        float Fy = guy * (1.0f - al) - gay * al;
        Fx = fminf(fmaxf(Fx, -4.35f), 4.35f);   // ma = DD - SIGMA
        Fy = fminf(fmaxf(Fy, -4.35f), 4.35f);
        mu[c * NF2 + id] = px + 0.2f * Fx;       // DT = 0.2
        mu[(3 + c) * NF2 + id] = py + 0.2f * Fy;
    }
}

// Reintegration: gather over exact 5x5 support (shifts beyond +-2 have area == 0).
__global__ __launch_bounds__(256) void k_reint(const float* __restrict__ A,
                                               const float* __restrict__ mu,
                                               float* __restrict__ out) {
    __shared__ float sA[3][36 * 36];
    __shared__ float sM[6][36 * 36];
    int tid = threadIdx.x;
    int x0 = blockIdx.x * 32, y0 = blockIdx.y * 32;
    for (int i = tid; i < 36 * 36; i += 256) {
        int lx = i / 36, ly = i - lx * 36;
        int xg = (x0 - 2 + lx) & (NF - 1);
        int yg = (y0 - 2 + ly) & (NF - 1);
        int gid = xg * NF + yg;
        sA[0][i] = A[gid * 3 + 0];
        sA[1][i] = A[gid * 3 + 1];
        sA[2][i] = A[gid * 3 + 2];
#pragma unroll
        for (int p = 0; p < 6; ++p) sM[p][i] = mu[p * NF2 + gid];
    }
    __syncthreads();

    const float INV_NORM = (float)(1.0 / (4.0 * 0.65 * 0.65));
    int cy = tid & 31, cx0 = tid >> 5;
    for (int sidx = 0; sidx < 4; ++sidx) {
        int cx = cx0 + 8 * sidx;
        int x = x0 + cx, y = y0 + cy;
        float px = (float)x + 0.5f, py = (float)y + 0.5f;
        float acc0 = 0.f, acc1 = 0.f, acc2 = 0.f;
#pragma unroll
        for (int dx = 0; dx < 5; ++dx)
#pragma unroll
            for (int dy = 0; dy < 5; ++dy) {
                int li = (cx + dx) * 36 + (cy + dy);
#pragma unroll
                for (int c = 0; c < 3; ++c) {
                    float mux = sM[c][li], muy = sM[3 + c][li];
                    float szx = 0.5f - fabsf(px - mux) + 0.65f;
                    float szy = 0.5f - fabsf(py - muy) + 0.65f;
                    szx = fminf(fmaxf(szx, 0.0f), 1.0f);
                    szy = fminf(fmaxf(szy, 0.0f), 1.0f);
                    float area = szx * szy * INV_NORM;
                    float v = sA[c][li] * area;
                    if (c == 0) acc0 += v;
                    else if (c == 1) acc1 += v;
                    else acc2 += v;
                }
            }
        int gid = x * NF + y;
        out[gid * 3 + 0] = acc0;
        out[gid * 3 + 1] = acc1;
        out[gid * 3 + 2] = acc2;
    }
}

extern "C" void kernel_launch(void* const* d_in, const int* in_sizes, int n_in,
                              void* d_out, int out_size, void* d_ws, size_t ws_size,
                              hipStream_t stream) {
    (void)in_sizes; (void)n_in; (void)out_size; (void)ws_size;
    const float* A  = (const float*)d_in[0];
    const float* nK = (const float*)d_in[1];
    const float* m  = (const float*)d_in[2];
    const float* s  = (const float*)d_in[3];
    const float* h  = (const float*)d_in[4];
    const int*   c0 = (const int*)d_in[5];
    const int*   c1 = (const int*)d_in[6];
    float* out = (float*)d_out;

    char* ws = (char*)d_ws;
    // Z: 7 packed complex planes = 14,680,064 B @ 0;  tmp: 5 planes @ 14,680,064.
    // Aliases into dead regions: G @0 (Z dead after mulinv), Up @10,485,760,
    // As @13,631,488, mu @14,680,064 (tmp dead after inv_p2g). Total 25.2 MB.
    float2* Z   = (float2*)ws;
    float2* tmp = (float2*)(ws + 14680064);
    float*  G   = (float*)ws;
    float*  Up  = (float*)(ws + 10485760);
    float*  As  = (float*)(ws + 13631488);
    float*  mu  = (float*)(ws + 14680064);

    dim3 blk(256);
    k_fwd_p1<<<dim3(NF / RPB, 7), blk, 0, stream>>>(A, nK, Z);
    k_fft_rows<<<dim3(7 * NF / RPB), blk, 0, stream>>>(Z, -1.0f);
    k_mulinv_p1<<<dim3(NF / RPB, 5), blk, 0, stream>>>(Z, c0, tmp);
    k_inv_p2g<<<dim3(NF / RPB, 5),   blk, 0, stream>>>(tmp, m, s, h, G);
    k_combine<<<dim3(NF2 / 256), blk, 0, stream>>>(G, c1, A, Up, As);
    k_flow<<<dim3(NF2 / 256),    blk, 0, stream>>>(Up, As, A, mu);
    k_reint<<<dim3(16, 16),      blk, 0, stream>>>(A, mu, out);
}

// Round 8
// 134.991 us; speedup vs baseline: 1.1539x; 1.0559x over previous
//
#include <hip/hip_runtime.h>
#include <math.h>

#define NF 512
#define NF2 (NF * NF)
#define RPB 4                 // FFT rows per block (4 rows x 64 threads)
#define ROWLEN 580            // LPAD(511)=574 max; 580 -> row stride % 32 words == 8
#define PI_F 3.14159265358979323846f

#define LPAD(q) ((q) + ((q) >> 3))   // LDS pad: 4 words/bank on butterfly writes

__device__ inline float2 cadd(float2 a, float2 b) { return make_float2(a.x + b.x, a.y + b.y); }
__device__ inline float2 csub(float2 a, float2 b) { return make_float2(a.x - b.x, a.y - b.y); }
__device__ inline float2 cmul(float2 a, float2 b) {
    return make_float2(a.x * b.x - a.y * b.y, a.x * b.y + a.y * b.x);
}

// 8-point DFT in registers, natural order in/out. dsign=-1 fwd, +1 inv.
__device__ inline void fft8(float2 x[8], float dsign) {
    const float s = 0.70710678118654752440f;
    float2 a0 = cadd(x[0], x[4]), a1 = cadd(x[1], x[5]);
    float2 a2 = cadd(x[2], x[6]), a3 = cadd(x[3], x[7]);
    float2 b0 = csub(x[0], x[4]), b1 = csub(x[1], x[5]);
    float2 b2 = csub(x[2], x[6]), b3 = csub(x[3], x[7]);
    b1 = cmul(b1, make_float2(s, dsign * s));
    b2 = make_float2(-dsign * b2.y, dsign * b2.x);
    b3 = cmul(b3, make_float2(-s, dsign * s));
    float2 c0 = cadd(a0, a2), c1 = cadd(a1, a3);
    float2 c2 = csub(a0, a2), c3 = csub(a1, a3);
    c3 = make_float2(-dsign * c3.y, dsign * c3.x);
    float2 d0 = cadd(b0, b2), d1 = cadd(b1, b3);
    float2 d2 = csub(b0, b2), d3 = csub(b1, b3);
    d3 = make_float2(-dsign * d3.y, dsign * d3.x);
    x[0] = cadd(c0, c1); x[4] = csub(c0, c1);
    x[2] = cadd(c2, c3); x[6] = csub(c2, c3);
    x[1] = cadd(d0, d1); x[5] = csub(d0, d1);
    x[3] = cadd(d2, d3); x[7] = csub(d2, d3);
}

__device__ inline void twiddle8(float2 x[8], float2 wb) {
    float2 tw = wb;
    x[1] = cmul(x[1], tw); tw = cmul(tw, wb);
    x[2] = cmul(x[2], tw); tw = cmul(tw, wb);
    x[3] = cmul(x[3], tw); tw = cmul(tw, wb);
    x[4] = cmul(x[4], tw); tw = cmul(tw, wb);
    x[5] = cmul(x[5], tw); tw = cmul(tw, wb);
    x[6] = cmul(x[6], tw); tw = cmul(tw, wb);
    x[7] = cmul(x[7], tw);
}

// Radix-8 Stockham FFT-512. In: x[j] = data[b + 64j]. Out: x[p] = Y[64p + b].
// 2 internal barriers; after return bufA is reusable, bufB is NOT.
__device__ inline void fft512_regs(float2 x[8], int b, float2* bufA, float2* bufB,
                                   const float2* Wt, float dsign) {
    fft8(x, dsign);
    float2 wb0 = make_float2(Wt[b].x, dsign * Wt[b].y);
    twiddle8(x, wb0);
#pragma unroll
    for (int p = 0; p < 8; ++p) bufA[9 * b + p] = x[p];   // LPAD(8b+p) = 9b+p
    __syncthreads();
#pragma unroll
    for (int j = 0; j < 8; ++j) x[j] = bufA[LPAD(b + 64 * j)];
    fft8(x, dsign);
    int u = b >> 3, v = b & 7;
    float2 wb1 = make_float2(Wt[b & ~7].x, dsign * Wt[b & ~7].y);   // W512[8u]
    twiddle8(x, wb1);
    int base = u * 64 + v;
#pragma unroll
    for (int p = 0; p < 8; ++p) bufB[LPAD(base + 8 * p)] = x[p];
    __syncthreads();
#pragma unroll
    for (int j = 0; j < 8; ++j) x[j] = bufB[LPAD(b + 64 * j)];
    fft8(x, dsign);
}

#define FFT_PRE                                                    \
    __shared__ float2 SHA[RPB][ROWLEN];                            \
    __shared__ float2 SHB[RPB][ROWLEN];                            \
    __shared__ float2 Wt[512];                                     \
    int tid = threadIdx.x;                                         \
    int rr_ = tid >> 6, bb_ = tid & 63;                            \
    {                                                              \
        float sn, cs;                                              \
        sincosf((PI_F / 256.0f) * (float)tid, &sn, &cs);           \
        Wt[tid] = make_float2(cs, sn);                             \
        sincosf((PI_F / 256.0f) * (float)(tid + 256), &sn, &cs);   \
        Wt[tid + 256] = make_float2(cs, sn);                       \
    }

// Hermitian unpack of one real field from a packed complex spectrum.
__device__ inline float2 unpack_field(const float2* __restrict__ Z, int plane, int slot,
                                      int ky, int kx) {
    const float2* P = Z + (size_t)plane * NF2;
    float2 zr = P[(ky << 9) + kx];
    float2 zm = P[(((NF - ky) & (NF - 1)) << 9) + ((NF - kx) & (NF - 1))];
    if (slot == 0)
        return make_float2(0.5f * (zr.x + zm.x), 0.5f * (zr.y - zm.y));
    else
        return make_float2(0.5f * (zr.y + zm.y), 0.5f * (zm.x - zr.x));
}

// Pass 1 forward, packed pairs of real planes:
//  p0=A0+iA1  p1=A2+iK0  p2=K1+iK2  p3=K3+iK4  p4=K5+iK6  p5=K7+iK8  p6=K9
__global__ __launch_bounds__(256) void k_fwd_p1(const float* __restrict__ A,
                                                const float* __restrict__ K,
                                                float2* __restrict__ Z) {
    FFT_PRE
    int pl = blockIdx.y;
    const float* bre; int sre, cre;
    const float* bim; int sim, cim;
    switch (pl) {
        case 0: bre = A; sre = 3; cre = 0; bim = A; sim = 3; cim = 1; break;
        case 1: bre = A; sre = 3; cre = 2; bim = K; sim = 10; cim = 0; break;
        case 2: bre = K; sre = 10; cre = 1; bim = K; sim = 10; cim = 2; break;
        case 3: bre = K; sre = 10; cre = 3; bim = K; sim = 10; cim = 4; break;
        case 4: bre = K; sre = 10; cre = 5; bim = K; sim = 10; cim = 6; break;
        case 5: bre = K; sre = 10; cre = 7; bim = K; sim = 10; cim = 8; break;
        default: bre = K; sre = 10; cre = 9; bim = nullptr; sim = 0; cim = 0; break;
    }
    int x0 = blockIdx.x * RPB;
    int row = x0 + rr_;
    float2 x[8];
#pragma unroll
    for (int j = 0; j < 8; ++j) {
        int idx = (row << 9) + bb_ + 64 * j;
        float vr = bre[idx * sre + cre];
        float vi = bim ? bim[idx * sim + cim] : 0.0f;
        x[j] = make_float2(vr, vi);
    }
    __syncthreads();                       // Wt table ready
    fft512_regs(x, bb_, &SHA[rr_][0], &SHB[rr_][0], Wt, -1.0f);
#pragma unroll
    for (int p2 = 0; p2 < 8; ++p2) SHA[rr_][LPAD(64 * p2 + bb_)] = x[p2];
    __syncthreads();
    for (int i = tid; i < RPB * NF; i += 256) {
        int r2 = i & (RPB - 1), ky = i >> 2;
        Z[(size_t)((pl << 9) + ky) * NF + x0 + r2] = SHA[r2][LPAD(ky)];
    }
}

// Pass 2: in-place FFT of contiguous rows (all 7 packed planes, one launch).
__global__ __launch_bounds__(256) void k_fft_rows(float2* __restrict__ data, float dsign) {
    FFT_PRE
    int R0 = blockIdx.x * RPB;
    size_t rowbase = (size_t)(R0 + rr_) * NF;
    float2 x[8];
#pragma unroll
    for (int j = 0; j < 8; ++j) x[j] = data[rowbase + bb_ + 64 * j];
    __syncthreads();
    fft512_regs(x, bb_, &SHA[rr_][0], &SHB[rr_][0], Wt, dsign);
#pragma unroll
    for (int p2 = 0; p2 < 8; ++p2) SHA[rr_][LPAD(64 * p2 + bb_)] = x[p2];
    __syncthreads();
    for (int i = tid; i < RPB * NF; i += 256) {
        int r2 = i >> 9, xx = i & (NF - 1);
        data[(size_t)(R0 + r2) * NF + xx] = SHA[r2][LPAD(xx)];
    }
}

// Paired spectral multiply + inverse FFT along kx, transposed store tmp[j][x][ky].
__global__ __launch_bounds__(256) void k_mulinv_p1(const float2* __restrict__ Z,
                                                   const int* __restrict__ c0,
                                                   float2* __restrict__ tmp) {
    FFT_PRE
    int jp = blockIdx.y;
    int k1 = 2 * jp, k2 = 2 * jp + 1;
    int pK1 = (k1 == 0) ? 1 : 2 + ((k1 - 1) >> 1);
    int sK1 = (k1 == 0) ? 1 : ((k1 - 1) & 1);
    int pK2 = 2 + ((k2 - 1) >> 1);
    int sK2 = (k2 - 1) & 1;
    int cA1 = c0[k1], cA2 = c0[k2];
    int pA1 = cA1 >> 1, sA1 = cA1 & 1;
    int pA2 = cA2 >> 1, sA2 = cA2 & 1;
    bool sameA = (cA1 == cA2);

    int ky0 = blockIdx.x * RPB;
    int ky = ky0 + rr_;
    float2 x[8];
#pragma unroll
    for (int jj = 0; jj < 8; ++jj) {
        int kx = bb_ + 64 * jj;
        float2 fk1 = unpack_field(Z, pK1, sK1, ky, kx);
        float2 fk2 = unpack_field(Z, pK2, sK2, ky, kx);
        float2 fa1 = unpack_field(Z, pA1, sA1, ky, kx);
        float2 fa2 = sameA ? fa1 : unpack_field(Z, pA2, sA2, ky, kx);
        float t1x = fk1.x * fa1.x - fk1.y * fa1.y;
        float t1y = fk1.x * fa1.y + fk1.y * fa1.x;
        float t2x = fk2.x * fa2.x - fk2.y * fa2.y;
        float t2y = fk2.x * fa2.y + fk2.y * fa2.x;
        float sgn = ((kx + ky) & 1) ? -1.0f : 1.0f;
        x[jj] = make_float2((t1x - t2y) * sgn, (t1y + t2x) * sgn);
    }
    __syncthreads();
    fft512_regs(x, bb_, &SHA[rr_][0], &SHB[rr_][0], Wt, +1.0f);
#pragma unroll
    for (int p2 = 0; p2 < 8; ++p2) SHA[rr_][LPAD(64 * p2 + bb_)] = x[p2];
    __syncthreads();
    for (int i = tid; i < RPB * NF; i += 256) {
        int r2 = i & (RPB - 1), xx = i >> 2;
        tmp[(size_t)(jp * NF + xx) * NF + ky0 + r2] = SHA[r2][LPAD(xx)];
    }
}

// Inverse FFT along ky + dual growth epilogue, coalesced store straight from regs.
__global__ __launch_bounds__(256) void k_inv_p2g(const float2* __restrict__ tmp,
                                                 const float* __restrict__ mm,
                                                 const float* __restrict__ ss,
                                                 const float* __restrict__ hh,
                                                 float* __restrict__ G) {
    FFT_PRE
    int jp = blockIdx.y;
    int k1 = 2 * jp, k2 = 2 * jp + 1;
    int x0 = blockIdx.x * RPB;
    int row = x0 + rr_;
    size_t base = (size_t)(jp * NF + row) * NF;
    float2 x[8];
#pragma unroll
    for (int j2 = 0; j2 < 8; ++j2) x[j2] = tmp[base + bb_ + 64 * j2];
    __syncthreads();
    fft512_regs(x, bb_, &SHA[rr_][0], &SHB[rr_][0], Wt, +1.0f);
    float m1 = mm[k1], s1 = ss[k1], h1 = hh[k1];
    float m2 = mm[k2], s2 = ss[k2], h2 = hh[k2];
    float i2s1 = 1.0f / (2.0f * s1 * s1);
    float i2s2 = 1.0f / (2.0f * s2 * s2);
    const float scale = 1.0f / ((float)NF * (float)NF);
#pragma unroll
    for (int p2 = 0; p2 < 8; ++p2) {
        int y = 64 * p2 + bb_;
        float u1 = x[p2].x * scale, u2 = x[p2].y * scale;
        float d1 = u1 - m1, d2 = u2 - m2;
        size_t o = (size_t)row * NF + y;
        G[(size_t)k1 * NF2 + o] = (2.0f * expf(-d1 * d1 * i2s1) - 1.0f) * h1;
        G[(size_t)k2 * NF2 + o] = (2.0f * expf(-d2 * d2 * i2s2) - 1.0f) * h2;
    }
}

// ---- Fused tail: combine + flow + reintegration in one kernel (halo recompute). ----
// Block = 32x32 output tile. Stage1: G/A -> Up,As,A on 38x38 halo tile (halo 3).
// Stage2: Sobel + alpha + clamp -> mu on 36x36 (halo 2). Stage3: 5x5 gather.
#define HT 38
#define HT2 (HT * HT)
#define CT 36
#define CT2 (CT * CT)
__global__ __launch_bounds__(256) void k_tail(const float* __restrict__ G,
                                              const int* __restrict__ c1,
                                              const float* __restrict__ A,
                                              float* __restrict__ out) {
    __shared__ float sUp[3][HT2];
    __shared__ float sAs[HT2];
    __shared__ float sA[3][HT2];
    __shared__ float sM[6][CT2];
    int tid = threadIdx.x;
    int X0 = blockIdx.x * 32, Y0 = blockIdx.y * 32;

    float w0[10], w1[10], w2[10];
#pragma unroll
    for (int k = 0; k < 10; ++k) {
        w0[k] = (float)c1[k * 3 + 0];
        w1[k] = (float)c1[k * 3 + 1];
        w2[k] = (float)c1[k * 3 + 2];
    }

    // Stage 1: 38x38 halo tile of Up (kernel->channel reduce), A, As.
    for (int i = tid; i < HT2; i += 256) {
        int lx = i / HT, ly = i - lx * HT;
        int xg = (X0 - 3 + lx) & (NF - 1);
        int yg = (Y0 - 3 + ly) & (NF - 1);
        int gid = xg * NF + yg;
        float a0 = 0.f, a1 = 0.f, a2 = 0.f;
#pragma unroll
        for (int k = 0; k < 10; ++k) {
            float g = G[(size_t)k * NF2 + gid];
            a0 += g * w0[k]; a1 += g * w1[k]; a2 += g * w2[k];
        }
        sUp[0][i] = a0; sUp[1][i] = a1; sUp[2][i] = a2;
        float A0 = A[gid * 3 + 0], A1 = A[gid * 3 + 1], A2 = A[gid * 3 + 2];
        sA[0][i] = A0; sA[1][i] = A1; sA[2][i] = A2;
        sAs[i] = A0 + A1 + A2;
    }
    __syncthreads();

    // Stage 2: mu on 36x36 (source cells' own wrapped absolute coords).
    for (int i = tid; i < CT2; i += 256) {
        int lx = i / CT, ly = i - lx * CT;
        int ci = (lx + 1) * HT + (ly + 1);
        int xg = (X0 - 2 + lx) & (NF - 1);
        int yg = (Y0 - 2 + ly) & (NF - 1);

        auto grad38 = [&](const float* f, float& gx, float& gy) {
            float fmm = f[ci - HT - 1], fm0 = f[ci - HT], fmp = f[ci - HT + 1];
            float f0m = f[ci - 1], f0p = f[ci + 1];
            float fpm = f[ci + HT - 1], fp0 = f[ci + HT], fpp = f[ci + HT + 1];
            gx = (fpm + 2.0f * fp0 + fpp - fmm - 2.0f * fm0 - fmp) * 0.125f;
            gy = (fmp + 2.0f * f0p + fpp - fmm - 2.0f * f0m - fpm) * 0.125f;
        };
        float gax, gay;
        grad38(sAs, gax, gay);
        float px = (float)xg + 0.5f, py = (float)yg + 0.5f;
#pragma unroll
        for (int c = 0; c < 3; ++c) {
            float gux, guy;
            grad38(sUp[c], gux, guy);
            float a = sA[c][ci];
            float al = fminf(a * a, 1.0f);
            float Fx = gux * (1.0f - al) - gax * al;
            float Fy = guy * (1.0f - al) - gay * al;
            Fx = fminf(fmaxf(Fx, -4.35f), 4.35f);   // ma = DD - SIGMA
            Fy = fminf(fmaxf(Fy, -4.35f), 4.35f);
            sM[c][i] = px + 0.2f * Fx;               // DT = 0.2
            sM[3 + c][i] = py + 0.2f * Fy;
        }
    }
    __syncthreads();

    // Stage 3: 5x5 reintegration gather (shifts beyond +-2 have exactly zero area).
    const float INV_NORM = (float)(1.0 / (4.0 * 0.65 * 0.65));
    int cy = tid & 31, cx0 = tid >> 5;
    for (int sidx = 0; sidx < 4; ++sidx) {
        int cx = cx0 + 8 * sidx;
        int x = X0 + cx, y = Y0 + cy;
        float px = (float)x + 0.5f, py = (float)y + 0.5f;
        float acc0 = 0.f, acc1 = 0.f, acc2 = 0.f;
#pragma unroll
        for (int dx = 0; dx < 5; ++dx)
#pragma unroll
            for (int dy = 0; dy < 5; ++dy) {
                int li36 = (cx + dx) * CT + (cy + dy);
                int li38 = (cx + dx + 1) * HT + (cy + dy + 1);
#pragma unroll
                for (int c = 0; c < 3; ++c) {
                    float mux = sM[c][li36], muy = sM[3 + c][li36];
                    float szx = 0.5f - fabsf(px - mux) + 0.65f;
                    float szy = 0.5f - fabsf(py - muy) + 0.65f;
                    szx = fminf(fmaxf(szx, 0.0f), 1.0f);
                    szy = fminf(fmaxf(szy, 0.0f), 1.0f);
                    float area = szx * szy * INV_NORM;
                    float v = sA[c][li38] * area;
                    if (c == 0) acc0 += v;
                    else if (c == 1) acc1 += v;
                    else acc2 += v;
                }
            }
        int gid = x * NF + y;
        out[gid * 3 + 0] = acc0;
        out[gid * 3 + 1] = acc1;
        out[gid * 3 + 2] = acc2;
    }
}

extern "C" void kernel_launch(void* const* d_in, const int* in_sizes, int n_in,
                              void* d_out, int out_size, void* d_ws, size_t ws_size,
                              hipStream_t stream) {
    (void)in_sizes; (void)n_in; (void)out_size; (void)ws_size;
    const float* A  = (const float*)d_in[0];
    const float* nK = (const float*)d_in[1];
    const float* m  = (const float*)d_in[2];
    const float* s  = (const float*)d_in[3];
    const float* h  = (const float*)d_in[4];
    const int*   c0 = (const int*)d_in[5];
    const int*   c1 = (const int*)d_in[6];
    float* out = (float*)d_out;

    char* ws = (char*)d_ws;
    // Z: 7 packed complex planes = 14,680,064 B @ 0;  tmp: 5 planes @ 14,680,064.
    // G (10 real planes, 10.5 MB) aliases Z (dead after mulinv). Total 25.2 MB.
    float2* Z   = (float2*)ws;
    float2* tmp = (float2*)(ws + 14680064);
    float*  G   = (float*)ws;

    dim3 blk(256);
    k_fwd_p1<<<dim3(NF / RPB, 7), blk, 0, stream>>>(A, nK, Z);
    k_fft_rows<<<dim3(7 * NF / RPB), blk, 0, stream>>>(Z, -1.0f);
    k_mulinv_p1<<<dim3(NF / RPB, 5), blk, 0, stream>>>(Z, c0, tmp);
    k_inv_p2g<<<dim3(NF / RPB, 5),   blk, 0, stream>>>(tmp, m, s, h, G);
    k_tail<<<dim3(16, 16), blk, 0, stream>>>(G, c1, A, out);
}

// Round 10
// 130.045 us; speedup vs baseline: 1.1978x; 1.0380x over previous
//
#include <hip/hip_runtime.h>
#include <math.h>

#define NF 512
#define NF2 (NF * NF)
#define RPB 4                 // FFT rows per block in 256-thread kernels
#define ROWLEN 580            // padded scratch row length (LPAD(511)=574 max)
#define PI_F 3.14159265358979323846f

#define LPAD(q) ((q) + ((q) >> 3))   // LDS pad for butterfly scatter

__device__ inline float2 cadd(float2 a, float2 b) { return make_float2(a.x + b.x, a.y + b.y); }
__device__ inline float2 csub(float2 a, float2 b) { return make_float2(a.x - b.x, a.y - b.y); }
__device__ inline float2 cmul(float2 a, float2 b) {
    return make_float2(a.x * b.x - a.y * b.y, a.x * b.y + a.y * b.x);
}

// 8-point DFT in registers, natural order in/out. dsign=-1 fwd, +1 inv.
__device__ inline void fft8(float2 x[8], float dsign) {
    const float s = 0.70710678118654752440f;
    float2 a0 = cadd(x[0], x[4]), a1 = cadd(x[1], x[5]);
    float2 a2 = cadd(x[2], x[6]), a3 = cadd(x[3], x[7]);
    float2 b0 = csub(x[0], x[4]), b1 = csub(x[1], x[5]);
    float2 b2 = csub(x[2], x[6]), b3 = csub(x[3], x[7]);
    b1 = cmul(b1, make_float2(s, dsign * s));
    b2 = make_float2(-dsign * b2.y, dsign * b2.x);
    b3 = cmul(b3, make_float2(-s, dsign * s));
    float2 c0 = cadd(a0, a2), c1 = cadd(a1, a3);
    float2 c2 = csub(a0, a2), c3 = csub(a1, a3);
    c3 = make_float2(-dsign * c3.y, dsign * c3.x);
    float2 d0 = cadd(b0, b2), d1 = cadd(b1, b3);
    float2 d2 = csub(b0, b2), d3 = csub(b1, b3);
    d3 = make_float2(-dsign * d3.y, dsign * d3.x);
    x[0] = cadd(c0, c1); x[4] = csub(c0, c1);
    x[2] = cadd(c2, c3); x[6] = csub(c2, c3);
    x[1] = cadd(d0, d1); x[5] = csub(d0, d1);
    x[3] = cadd(d2, d3); x[7] = csub(d2, d3);
}

__device__ inline void twiddle8(float2 x[8], float2 wb) {
    float2 tw = wb;
    x[1] = cmul(x[1], tw); tw = cmul(tw, wb);
    x[2] = cmul(x[2], tw); tw = cmul(tw, wb);
    x[3] = cmul(x[3], tw); tw = cmul(tw, wb);
    x[4] = cmul(x[4], tw); tw = cmul(tw, wb);
    x[5] = cmul(x[5], tw); tw = cmul(tw, wb);
    x[6] = cmul(x[6], tw); tw = cmul(tw, wb);
    x[7] = cmul(x[7], tw);
}

// Radix-8 Stockham FFT-512. In: x[j] = data[b + 64j]. Out: x[p] = Y[64p + b].
// Uses per-wavegroup scratch bufA/bufB; 2 internal block barriers (all threads
// of the block must call together). Safe to reuse bufA after return.
__device__ inline void fft512_regs(float2 x[8], int b, float2* bufA, float2* bufB,
                                   const float2* Wt, float dsign) {
    fft8(x, dsign);
    float2 wb0 = make_float2(Wt[b].x, dsign * Wt[b].y);
    twiddle8(x, wb0);
#pragma unroll
    for (int p = 0; p < 8; ++p) bufA[9 * b + p] = x[p];   // LPAD(8b+p) = 9b+p
    __syncthreads();
#pragma unroll
    for (int j = 0; j < 8; ++j) x[j] = bufA[LPAD(b + 64 * j)];
    fft8(x, dsign);
    int u = b >> 3, v = b & 7;
    float2 wb1 = make_float2(Wt[b & ~7].x, dsign * Wt[b & ~7].y);   // W512[8u]
    twiddle8(x, wb1);
    int base = u * 64 + v;
#pragma unroll
    for (int p = 0; p < 8; ++p) bufB[LPAD(base + 8 * p)] = x[p];
    __syncthreads();
#pragma unroll
    for (int j = 0; j < 8; ++j) x[j] = bufB[LPAD(b + 64 * j)];
    fft8(x, dsign);
}

#define FFT_PRE                                                    \
    __shared__ float2 SHA[RPB][ROWLEN];                            \
    __shared__ float2 SHB[RPB][ROWLEN];                            \
    __shared__ float2 Wt[512];                                     \
    int tid = threadIdx.x;                                         \
    int rr_ = tid >> 6, bb_ = tid & 63;                            \
    {                                                              \
        float sn, cs;                                              \
        sincosf((PI_F / 256.0f) * (float)tid, &sn, &cs);           \
        Wt[tid] = make_float2(cs, sn);                             \
        sincosf((PI_F / 256.0f) * (float)(tid + 256), &sn, &cs);   \
        Wt[tid + 256] = make_float2(cs, sn);                       \
    }

// Pass 1 forward, packed pairs of real planes:
//  p0=A0+iA1  p1=A2+iK0  p2=K1+iK2  p3=K3+iK4  p4=K5+iK6  p5=K7+iK8  p6=K9
// FFT along y, transposed store: Z[p][ky][x].
__global__ __launch_bounds__(256) void k_fwd_p1(const float* __restrict__ A,
                                                const float* __restrict__ K,
                                                float2* __restrict__ Z) {
    FFT_PRE
    int pl = blockIdx.y;
    const float* bre; int sre, cre;
    const float* bim; int sim, cim;
    switch (pl) {
        case 0: bre = A; sre = 3; cre = 0; bim = A; sim = 3; cim = 1; break;
        case 1: bre = A; sre = 3; cre = 2; bim = K; sim = 10; cim = 0; break;
        case 2: bre = K; sre = 10; cre = 1; bim = K; sim = 10; cim = 2; break;
        case 3: bre = K; sre = 10; cre = 3; bim = K; sim = 10; cim = 4; break;
        case 4: bre = K; sre = 10; cre = 5; bim = K; sim = 10; cim = 6; break;
        case 5: bre = K; sre = 10; cre = 7; bim = K; sim = 10; cim = 8; break;
        default: bre = K; sre = 10; cre = 9; bim = nullptr; sim = 0; cim = 0; break;
    }
    int x0 = blockIdx.x * RPB;
    int row = x0 + rr_;
    float2 x[8];
#pragma unroll
    for (int j = 0; j < 8; ++j) {
        int idx = (row << 9) + bb_ + 64 * j;
        float vr = bre[idx * sre + cre];
        float vi = bim ? bim[idx * sim + cim] : 0.0f;
        x[j] = make_float2(vr, vi);
    }
    __syncthreads();                       // Wt table ready
    fft512_regs(x, bb_, &SHA[rr_][0], &SHB[rr_][0], Wt, -1.0f);
#pragma unroll
    for (int p2 = 0; p2 < 8; ++p2) SHA[rr_][LPAD(64 * p2 + bb_)] = x[p2];
    __syncthreads();
    for (int i = tid; i < RPB * NF; i += 256) {
        int r2 = i & (RPB - 1), ky = i >> 2;
        Z[(size_t)((pl << 9) + ky) * NF + x0 + r2] = SHA[r2][LPAD(ky)];
    }
}

// ---- Fused: row-FFT (completes forward 2D) + spectral products + kx-inverse-FFT.
// Block b owns rows (r1,r2) = (b, 512-b) for b=1..255; block 0 owns {0, 256}
// (self-mirror rows). All 7 packed planes' rows are FFT'd into LDS, so the
// Hermitian mirror (-ky,-kx) is block-local. Output natural: tmpT[j][ky][x].
__global__ __launch_bounds__(512) void k_rows_mul(const float2* __restrict__ Z,
                                                  const int* __restrict__ c0,
                                                  float2* __restrict__ tmpT) {
    __shared__ float2 RS[14][NF];          // [2*plane + slot][kx]; slot0=r1, slot1=r2
    __shared__ float2 SCA[8][ROWLEN];
    __shared__ float2 SCB[8][ROWLEN];
    __shared__ float2 Wt[512];
    int tid = threadIdx.x;
    int rr_ = tid >> 6, bb_ = tid & 63;    // 8 wave-groups x 64 lanes
    {
        float sn, cs;
        sincosf((PI_F / 256.0f) * (float)tid, &sn, &cs);
        Wt[tid] = make_float2(cs, sn);
    }
    int b = blockIdx.x;
    bool selfm = (b == 0);
    int r1 = selfm ? 0 : b;
    int r2 = selfm ? 256 : NF - b;
    __syncthreads();                        // Wt ready

    // Forward phase: FFT 14 rows (7 planes x {r1,r2}) in 2 batches of 8.
    for (int batch = 0; batch < 2; ++batch) {
        int ridx = batch * 8 + rr_;        // 0..15; valid < 14
        int rc = ridx < 14 ? ridx : 13;    // dummy groups redo row 13
        int p = rc >> 1, sl = rc & 1;
        int row = sl ? r2 : r1;
        float2 x[8];
        size_t base = (size_t)((p << 9) + row) * NF;
#pragma unroll
        for (int jj = 0; jj < 8; ++jj) x[jj] = Z[base + bb_ + 64 * jj];
        fft512_regs(x, bb_, &SCA[rr_][0], &SCB[rr_][0], Wt, -1.0f);
        if (ridx < 14) {
#pragma unroll
            for (int pp = 0; pp < 8; ++pp) RS[ridx][64 * pp + bb_] = x[pp];
        }
    }
    __syncthreads();                        // RS complete

    // Product phase: 10 product rows (5 j-planes x {r1,r2}) in 2 batches.
    for (int batch = 0; batch < 2; ++batch) {
        int q = batch * 8 + rr_;            // 0..15; valid < 10
        int qc = q < 10 ? q : 8;
        int j = qc >> 1, sl = qc & 1;
        int k1 = 2 * j, k2 = 2 * j + 1;
        int pK1 = (k1 == 0) ? 1 : 2 + ((k1 - 1) >> 1);
        int sK1 = (k1 == 0) ? 1 : ((k1 - 1) & 1);
        int pK2 = 2 + ((k2 - 1) >> 1);
        int sK2 = (k2 - 1) & 1;
        int cA1 = c0[k1], cA2 = c0[k2];
        int pA1 = cA1 >> 1, sA1 = cA1 & 1;
        int pA2 = cA2 >> 1, sA2 = cA2 & 1;
        int mo = selfm ? sl : (1 - sl);     // mirror row slot
        float2 x[8];
#pragma unroll
        for (int jj = 0; jj < 8; ++jj) {
            int kx = bb_ + 64 * jj;
            int mkx = (NF - kx) & (NF - 1);
            float2 zr, zm, fk1, fk2, fa1, fa2;
            zr = RS[2 * pK1 + sl][kx]; zm = RS[2 * pK1 + mo][mkx];
            fk1 = sK1 == 0 ? make_float2(0.5f * (zr.x + zm.x), 0.5f * (zr.y - zm.y))
                           : make_float2(0.5f * (zr.y + zm.y), 0.5f * (zm.x - zr.x));
            zr = RS[2 * pK2 + sl][kx]; zm = RS[2 * pK2 + mo][mkx];
            fk2 = sK2 == 0 ? make_float2(0.5f * (zr.x + zm.x), 0.5f * (zr.y - zm.y))
                           : make_float2(0.5f * (zr.y + zm.y), 0.5f * (zm.x - zr.x));
            zr = RS[2 * pA1 + sl][kx]; zm = RS[2 * pA1 + mo][mkx];
            fa1 = sA1 == 0 ? make_float2(0.5f * (zr.x + zm.x), 0.5f * (zr.y - zm.y))
                           : make_float2(0.5f * (zr.y + zm.y), 0.5f * (zm.x - zr.x));
            if (cA2 == cA1) fa2 = fa1;
            else {
                zr = RS[2 * pA2 + sl][kx]; zm = RS[2 * pA2 + mo][mkx];
                fa2 = sA2 == 0 ? make_float2(0.5f * (zr.x + zm.x), 0.5f * (zr.y - zm.y))
                               : make_float2(0.5f * (zr.y + zm.y), 0.5f * (zm.x - zr.x));
            }
            float t1x = fk1.x * fa1.x - fk1.y * fa1.y;
            float t1y = fk1.x * fa1.y + fk1.y * fa1.x;
            float t2x = fk2.x * fa2.x - fk2.y * fa2.y;
            float t2y = fk2.x * fa2.y + fk2.y * fa2.x;
            float sgn = ((kx + b) & 1) ? -1.0f : 1.0f;   // parity(r1)=parity(r2)=parity(b)
            x[jj] = make_float2((t1x - t2y) * sgn, (t1y + t2x) * sgn);
        }
        fft512_regs(x, bb_, &SCA[rr_][0], &SCB[rr_][0], Wt, +1.0f);
        if (q < 10) {
            int orow = sl ? r2 : r1;
            size_t obase = ((size_t)j * NF + orow) * NF;
#pragma unroll
            for (int pp = 0; pp < 8; ++pp) tmpT[obase + 64 * pp + bb_] = x[pp];
        }
    }
}

// Inverse FFT along ky (columns of tmpT[j][ky][x]) + dual growth epilogue.
// Block = (j, 4 x-columns): load 32 B/ky chunks, LDS-transpose, FFT, store G coalesced.
__global__ __launch_bounds__(256) void k_inv_p2g(const float2* __restrict__ tmpT,
                                                 const float* __restrict__ mm,
                                                 const float* __restrict__ ss,
                                                 const float* __restrict__ hh,
                                                 float* __restrict__ G) {
    __shared__ float2 SH[4][NF];
    __shared__ float2 SCA[4][ROWLEN];
    __shared__ float2 SCB[4][ROWLEN];
    __shared__ float2 Wt[512];
    int tid = threadIdx.x;
    int rr_ = tid >> 6, bb_ = tid & 63;
    {
        float sn, cs;
        sincosf((PI_F / 256.0f) * (float)tid, &sn, &cs);
        Wt[tid] = make_float2(cs, sn);
        sincosf((PI_F / 256.0f) * (float)(tid + 256), &sn, &cs);
        Wt[tid + 256] = make_float2(cs, sn);
    }
    int j = blockIdx.y;
    int x0 = blockIdx.x * 4;
    for (int t = tid; t < NF; t += 256) {
        const float2* src = tmpT + ((size_t)j * NF + t) * NF + x0;
        float4 v0 = *(const float4*)(src);
        float4 v1 = *(const float4*)(src + 2);
        SH[0][t] = make_float2(v0.x, v0.y);
        SH[1][t] = make_float2(v0.z, v0.w);
        SH[2][t] = make_float2(v1.x, v1.y);
        SH[3][t] = make_float2(v1.z, v1.w);
    }
    __syncthreads();
    float2 x[8];
#pragma unroll
    for (int jj = 0; jj < 8; ++jj) x[jj] = SH[rr_][bb_ + 64 * jj];
    fft512_regs(x, bb_, &SCA[rr_][0], &SCB[rr_][0], Wt, +1.0f);
    int k1 = 2 * j, k2 = 2 * j + 1;
    float m1 = mm[k1], s1 = ss[k1], h1 = hh[k1];
    float m2 = mm[k2], s2 = ss[k2], h2 = hh[k2];
    float i2s1 = 1.0f / (2.0f * s1 * s1);
    float i2s2 = 1.0f / (2.0f * s2 * s2);
    const float scale = 1.0f / ((float)NF * (float)NF);
    int xcol = x0 + rr_;
#pragma unroll
    for (int p2 = 0; p2 < 8; ++p2) {
        int y = 64 * p2 + bb_;
        float u1 = x[p2].x * scale, u2 = x[p2].y * scale;
        float d1 = u1 - m1, d2 = u2 - m2;
        size_t o = (size_t)xcol * NF + y;
        G[(size_t)k1 * NF2 + o] = (2.0f * expf(-d1 * d1 * i2s1) - 1.0f) * h1;
        G[(size_t)k2 * NF2 + o] = (2.0f * expf(-d2 * d2 * i2s2) - 1.0f) * h2;
    }
}

// ---- Fused tail: combine + flow + reintegration (halo recompute). ----
#define HT 38
#define HT2 (HT * HT)
#define CT 36
#define CT2 (CT * CT)
__global__ __launch_bounds__(256) void k_tail(const float* __restrict__ G,
                                              const int* __restrict__ c1,
                                              const float* __restrict__ A,
                                              float* __restrict__ out) {
    __shared__ float sUp[3][HT2];
    __shared__ float sAs[HT2];
    __shared__ float sA[3][HT2];
    __shared__ float sM[6][CT2];
    int tid = threadIdx.x;
    int X0 = blockIdx.x * 32, Y0 = blockIdx.y * 32;

    float w0[10], w1[10], w2[10];
#pragma unroll
    for (int k = 0; k < 10; ++k) {
        w0[k] = (float)c1[k * 3 + 0];
        w1[k] = (float)c1[k * 3 + 1];
        w2[k] = (float)c1[k * 3 + 2];
    }

    for (int i = tid; i < HT2; i += 256) {
        int lx = i / HT, ly = i - lx * HT;
        int xg = (X0 - 3 + lx) & (NF - 1);
        int yg = (Y0 - 3 + ly) & (NF - 1);
        int gid = xg * NF + yg;
        float a0 = 0.f, a1 = 0.f, a2 = 0.f;
#pragma unroll
        for (int k = 0; k < 10; ++k) {
            float g = G[(size_t)k * NF2 + gid];
            a0 += g * w0[k]; a1 += g * w1[k]; a2 += g * w2[k];
        }
        sUp[0][i] = a0; sUp[1][i] = a1; sUp[2][i] = a2;
        float A0 = A[gid * 3 + 0], A1 = A[gid * 3 + 1], A2 = A[gid * 3 + 2];
        sA[0][i] = A0; sA[1][i] = A1; sA[2][i] = A2;
        sAs[i] = A0 + A1 + A2;
    }
    __syncthreads();

    for (int i = tid; i < CT2; i += 256) {
        int lx = i / CT, ly = i - lx * CT;
        int ci = (lx + 1) * HT + (ly + 1);
        int xg = (X0 - 2 + lx) & (NF - 1);
        int yg = (Y0 - 2 + ly) & (NF - 1);

        auto grad38 = [&](const float* f, float& gx, float& gy) {
            float fmm = f[ci - HT - 1], fm0 = f[ci - HT], fmp = f[ci - HT + 1];
            float f0m = f[ci - 1], f0p = f[ci + 1];
            float fpm = f[ci + HT - 1], fp0 = f[ci + HT], fpp = f[ci + HT + 1];
            gx = (fpm + 2.0f * fp0 + fpp - fmm - 2.0f * fm0 - fmp) * 0.125f;
            gy = (fmp + 2.0f * f0p + fpp - fmm - 2.0f * f0m - fpm) * 0.125f;
        };
        float gax, gay;
        grad38(sAs, gax, gay);
        float px = (float)xg + 0.5f, py = (float)yg + 0.5f;
#pragma unroll
        for (int c = 0; c < 3; ++c) {
            float gux, guy;
            grad38(sUp[c], gux, guy);
            float a = sA[c][ci];
            float al = fminf(a * a, 1.0f);
            float Fx = gux * (1.0f - al) - gax * al;
            float Fy = guy * (1.0f - al) - gay * al;
            Fx = fminf(fmaxf(Fx, -4.35f), 4.35f);   // ma = DD - SIGMA
            Fy = fminf(fmaxf(Fy, -4.35f), 4.35f);
            sM[c][i] = px + 0.2f * Fx;               // DT = 0.2
            sM[3 + c][i] = py + 0.2f * Fy;
        }
    }
    __syncthreads();

    const float INV_NORM = (float)(1.0 / (4.0 * 0.65 * 0.65));
    int cy = tid & 31, cx0 = tid >> 5;
    for (int sidx = 0; sidx < 4; ++sidx) {
        int cx = cx0 + 8 * sidx;
        int x = X0 + cx, y = Y0 + cy;
        float px = (float)x + 0.5f, py = (float)y + 0.5f;
        float acc0 = 0.f, acc1 = 0.f, acc2 = 0.f;
#pragma unroll
        for (int dx = 0; dx < 5; ++dx)
#pragma unroll
            for (int dy = 0; dy < 5; ++dy) {
                int li36 = (cx + dx) * CT + (cy + dy);
                int li38 = (cx + dx + 1) * HT + (cy + dy + 1);
#pragma unroll
                for (int c = 0; c < 3; ++c) {
                    float mux = sM[c][li36], muy = sM[3 + c][li36];
                    float szx = 0.5f - fabsf(px - mux) + 0.65f;
                    float szy = 0.5f - fabsf(py - muy) + 0.65f;
                    szx = fminf(fmaxf(szx, 0.0f), 1.0f);
                    szy = fminf(fmaxf(szy, 0.0f), 1.0f);
                    float area = szx * szy * INV_NORM;
                    float v = sA[c][li38] * area;
                    if (c == 0) acc0 += v;
                    else if (c == 1) acc1 += v;
                    else acc2 += v;
                }
            }
        int gid = x * NF + y;
        out[gid * 3 + 0] = acc0;
        out[gid * 3 + 1] = acc1;
        out[gid * 3 + 2] = acc2;
    }
}

extern "C" void kernel_launch(void* const* d_in, const int* in_sizes, int n_in,
                              void* d_out, int out_size, void* d_ws, size_t ws_size,
                              hipStream_t stream) {
    (void)in_sizes; (void)n_in; (void)out_size; (void)ws_size;
    const float* A  = (const float*)d_in[0];
    const float* nK = (const float*)d_in[1];
    const float* m  = (const float*)d_in[2];
    const float* s  = (const float*)d_in[3];
    const float* h  = (const float*)d_in[4];
    const int*   c0 = (const int*)d_in[5];
    const int*   c1 = (const int*)d_in[6];
    float* out = (float*)d_out;

    char* ws = (char*)d_ws;
    // Z: 7 packed complex planes = 14,680,064 B @ 0; tmpT: 5 planes @ 14,680,064.
    // G (10 real planes, 10.5 MB) aliases Z (dead after k_rows_mul). Total 25.2 MB.
    float2* Z    = (float2*)ws;
    float2* tmpT = (float2*)(ws + 14680064);
    float*  G    = (float*)ws;

    k_fwd_p1<<<dim3(NF / RPB, 7), dim3(256), 0, stream>>>(A, nK, Z);
    k_rows_mul<<<dim3(256), dim3(512), 0, stream>>>(Z, c0, tmpT);
    k_inv_p2g<<<dim3(NF / 4, 5), dim3(256), 0, stream>>>(tmpT, m, s, h, G);
    k_tail<<<dim3(16, 16), dim3(256), 0, stream>>>(G, c1, A, out);
}